// Round 14
// baseline (72.721 us; speedup 1.0000x reference)
//
#include <hip/hip_runtime.h>

// Fused 3D SSIM, window 7^3, VALID. pred/targ: (4,1,32,320,320) f32.
// R13 skeleton (tile 16h x 26w outputs, full t-range, per-thread pair-colsum
// from float4-interleaved LDS, DPP row_shr w-gather, packed-f32 math,
// temporal 7-ring) with:
//  - 2-slice phases: 4 LDS slice buffers, ONE barrier per two slices.
//  - float4 global staging: 176 items x (2 x 16B loads), reg-interleaved to
//    the same (p0,p1,q0,q1) LDS layout (colsum read path unchanged).
//  - 2 slices of prefetch in flight (sets A/B), issued mid-phase.
// Fields: f0=sum p, f1=sum q, f2=sum p^2+q^2, f3=sum p*q.

#define NPIX 343

constexpr int B = 4, T = 32, H = 320, W = 320;
constexpr int TO = T - 6, HO = H - 6, WO = W - 6;   // 26, 314, 314
constexpr long long NOUT = (long long)B * TO * HO * WO;

constexpr int TH = 16, TW = 26;    // output tile
constexpr int IH = 22, IWP = 16;   // input tile: 22 rows x 16 pair-cols
constexpr int NTH = 20, NTW = 13;  // 20*16 >= 314; 13*26 >= 314

typedef float v2f __attribute__((ext_vector_type(2)));

template<int N>
__device__ __forceinline__ float row_shr(float x) {
    // lane i (within its 16-lane DPP row) receives lane i-N; OOB -> 0
    return __int_as_float(__builtin_amdgcn_update_dpp(
        0, __float_as_int(x), 0x110 | N, 0xF, 0xF, true));
}

__global__ __launch_bounds__(256) void ssim3d_fused(
    const float* __restrict__ pred,
    const float* __restrict__ targ,
    const float* __restrict__ drange,
    double* __restrict__ acc)
{
    __shared__ float4 spq[4][IH][IWP];   // 22528 B, (p0,p1,q0,q1)
    __shared__ float wsum[4];

    const int bx = blockIdx.x;
    const int b  = bx / (NTH * NTW);
    int rem      = bx % (NTH * NTW);
    const int h0 = (rem / NTW) * TH;
    const int w0 = (rem % NTW) * TW;

    const int tid = threadIdx.x;
    const int oh  = tid >> 4;   // 0..15
    const int k   = tid & 15;   // pair-column 0..15

    const float* pb = pred + (long long)b * T * H * W;
    const float* qb = targ + (long long)b * T * H * W;

    // ---- staging: 176 items = 22 rows x 8 quad-cols; item loads f4 p + f4 q
    const bool stager = (tid < 176);
    const int rs = tid >> 3;          // 0..21
    const int qc = tid & 7;           // 0..7 (cols 4qc..4qc+3 = pairs 2qc,2qc+1)
    const int grs = min(h0 + rs, H - 1), gcs = min(w0 + 4 * qc, W - 4);
    const float* gps = pb + (long long)grs * W + gcs;
    const float* gqs = qb + (long long)grs * W + gcs;

    float4 pA, qA, pB, qB;   // two slices in flight
    auto loadA = [&](int s) {
        if (stager) {
            const long long so = (long long)s * H * W;
            pA = *reinterpret_cast<const float4*>(gps + so);
            qA = *reinterpret_cast<const float4*>(gqs + so);
        }
    };
    auto loadB = [&](int s) {
        if (stager) {
            const long long so = (long long)s * H * W;
            pB = *reinterpret_cast<const float4*>(gps + so);
            qB = *reinterpret_cast<const float4*>(gqs + so);
        }
    };
    auto commitA = [&](int buf) {
        if (stager) {
            spq[buf][rs][2 * qc]     = make_float4(pA.x, pA.y, qA.x, qA.y);
            spq[buf][rs][2 * qc + 1] = make_float4(pA.z, pA.w, qA.z, qA.w);
        }
    };
    auto commitB = [&](int buf) {
        if (stager) {
            spq[buf][rs][2 * qc]     = make_float4(pB.x, pB.y, qB.x, qB.y);
            spq[buf][rs][2 * qc + 1] = make_float4(pB.z, pB.w, qB.z, qB.w);
        }
    };

    // ---- output mapping: thread k emits local cols 2k-6 (even), 2k-5 (odd)
    const bool vh = (h0 + oh < HO);
    const bool k3 = (k >= 3);
    const bool vE = k3 && vh && (w0 + 2 * k - 6 < WO);
    const bool vO = k3 && vh && (w0 + 2 * k - 5 < WO);

    const float dr  = drange[b];
    const float C1s = (0.01f * dr) * (0.01f * dr);
    const float C2s = (0.03f * dr) * (0.03f * dr);
    const float inv  = 1.0f / (float)NPIX;
    const float covn = (float)NPIX / (float)(NPIX - 1);
    const v2f invv  = {inv, inv};
    const v2f C1vv  = {C1s, C1s};
    const v2f C2vv  = {C2s, C2s};
    const v2f covnv = {covn, covn};
    const v2f c2cov = {2.f * covn, 2.f * covn};

    v2f rEO[4][7], tEO[4];
#pragma unroll
    for (int f = 0; f < 4; ++f) {
        tEO[f] = (v2f){0.f, 0.f};
#pragma unroll
        for (int j = 0; j < 7; ++j) rEO[f][j] = (v2f){0.f, 0.f};
    }
    float loss = 0.f;

    // ---- one slice's compute: colsum -> DPP gather -> ring -> emit ----
    auto compute = [&](int buf, int jj, bool doEmit) {
        v2f c0 = {0.f, 0.f}, c1v = {0.f, 0.f}, c2 = {0.f, 0.f}, c3 = {0.f, 0.f};
#pragma unroll
        for (int dy = 0; dy < 7; ++dy) {
            float4 v = spq[buf][oh + dy][k];
            v2f vp = {v.x, v.y};
            v2f vq = {v.z, v.w};
            c0 += vp;
            c1v += vq;
            c2 = __builtin_elementwise_fma(vp, vp, c2);
            c2 = __builtin_elementwise_fma(vq, vq, c2);
            c3 = __builtin_elementwise_fma(vp, vq, c3);
        }

        v2f sv[4];
        {
            v2f cf[4] = {c0, c1v, c2, c3};
#pragma unroll
            for (int f = 0; f < 4; ++f) {
                float ps = cf[f].x + cf[f].y;
                float t1 = ps + row_shr<1>(ps);
                float s8 = t1 + row_shr<2>(t1);      // pairs k-3..k
                float eL = row_shr<3>(cf[f].x);      // col 2k-6
                sv[f].x = s8 - cf[f].y;              // cols 2k-6..2k (even)
                sv[f].y = s8 - eL;                   // cols 2k-5..2k+1 (odd)
            }
        }

#pragma unroll
        for (int f = 0; f < 4; ++f) {
            tEO[f] += sv[f] - rEO[f][jj];
            rEO[f][jj] = sv[f];
        }

        if (doEmit) {
            v2f ux  = tEO[0] * invv;
            v2f uy  = tEO[1] * invv;
            v2f u2  = tEO[2] * invv;
            v2f uxy = tEO[3] * invv;
            v2f m   = __builtin_elementwise_fma(-ux, uy, uxy);
            v2f A2  = __builtin_elementwise_fma(c2cov, m, C2vv);
            v2f nb  = __builtin_elementwise_fma(-ux, ux, u2);
            nb      = __builtin_elementwise_fma(-uy, uy, nb);
            v2f B2  = __builtin_elementwise_fma(covnv, nb, C2vv);
            v2f ux2 = ux + ux;
            v2f A1  = __builtin_elementwise_fma(ux2, uy, C1vv);
            v2f B1  = __builtin_elementwise_fma(
                          ux, ux, __builtin_elementwise_fma(uy, uy, C1vv));
            v2f num = A1 * A2;
            v2f den = B1 * B2;
            float sx = __fdividef(num.x, den.x);
            float sy = __fdividef(num.y, den.y);
            if (vE) loss += 1.f - sx;
            if (vO) loss += 1.f - sy;
        }
    };

    // ---- phase: slices 2p, 2p+1; commit 2p+2,2p+3; prefetch 2p+4,2p+5 ----
    auto phase = [&](int p, int jj0, int jj1, bool doEmit,
                     bool doCommit, bool doPrefetch) {
        const int s0 = 2 * p;
        if (doCommit) {
            commitA((s0 + 2) & 3);
            commitB((s0 + 3) & 3);
        }
        if (doPrefetch) {
            loadA(s0 + 4);
            loadB(s0 + 5);
        }
        compute(s0 & 3, jj0, doEmit);
        compute((s0 + 1) & 3, jj1, doEmit);
        __syncthreads();
    };

    // ---- prologue: slices 0,1 committed; 2,3 in flight ----
    loadA(0);
    loadB(1);
    commitA(0);
    commitB(1);
    loadA(2);
    loadB(3);
    __syncthreads();

    // phases 0..6  (slices 0..13): emit from phase 3 (slice 6)
#pragma unroll
    for (int p = 0; p < 7; ++p)
        phase(p, (2 * p) % 7, (2 * p + 1) % 7, p >= 3, true, true);
    // phases 7..13 (slices 14..27)
#pragma unroll
    for (int p = 7; p < 14; ++p)
        phase(p, (2 * p) % 7, (2 * p + 1) % 7, true, true, true);
    // tail: phase 14 (slices 28,29; commit 30,31), phase 15 (slices 30,31)
    phase(14, 0, 1, true, true, false);
    phase(15, 2, 3, true, false, false);

    // ---- block reduction -> global atomic ----
    for (int off = 32; off > 0; off >>= 1)
        loss += __shfl_down(loss, off, 64);
    const int lane = tid & 63;
    const int wid  = tid >> 6;
    if (lane == 0) wsum[wid] = loss;
    __syncthreads();
    if (tid == 0) {
        float s = wsum[0] + wsum[1] + wsum[2] + wsum[3];
        atomicAdd(acc, (double)s);
    }
}

__global__ void ssim3d_finalize(const double* __restrict__ acc,
                                float* __restrict__ out)
{
    out[0] = (float)(acc[0] / (double)NOUT);
}

extern "C" void kernel_launch(void* const* d_in, const int* in_sizes, int n_in,
                              void* d_out, int out_size, void* d_ws, size_t ws_size,
                              hipStream_t stream)
{
    const float* pred   = (const float*)d_in[0];
    const float* targ   = (const float*)d_in[1];
    const float* drange = (const float*)d_in[2];
    float* out  = (float*)d_out;
    double* acc = (double*)d_ws;

    hipMemsetAsync(acc, 0, sizeof(double), stream);

    const int nblocks = B * NTH * NTW;  // 1040
    ssim3d_fused<<<nblocks, 256, 0, stream>>>(pred, targ, drange, acc);
    ssim3d_finalize<<<1, 1, 0, stream>>>(acc, out);
}